// Round 9
// baseline (511.966 us; speedup 1.0000x reference)
//
#include <hip/hip_runtime.h>
#include <hip/hip_cooperative_groups.h>

#define N_KER 64
#define K_PTS 16
#define LOG2E 1.44269504088896340736f
#define GRID_BLKS 2048          // 8 blocks/CU x 256 CUs -- all co-resident
#define PTS_PER_BLK 16          // 4 waves x 4 points

namespace cg = cooperative_groups;

// ============================================================================
// out[i][m] = (1/128) * (S[i][m]+S[a][m]+S[b][m]+S[c][m]),
// S[q][m] = sum_l exp(-||g_q - k[m][l]||^2), stored u8 (R8-proven, err margin
// 2.8x). R9: ONE cooperative kernel = phaseA (compute S) + grid.sync +
// phaseB (gather-add). Removes the inter-kernel drain/ramp + one launch.
// Phase internals byte-identical to R8 (one variable this round).
// ============================================================================
__global__ __launch_bounds__(256, 8) void corr_coop(
    const float*   __restrict__ normal,
    const int*     __restrict__ neighbour,
    const float*   __restrict__ kern,
    unsigned char* __restrict__ S,
    float4*        __restrict__ out4,
    int n)
{
    __shared__ float4 ksp[K_PTS * N_KER];   // 16 KB [l][m], conflict-free (R3+)

    const int tid = threadIdx.x;
    #pragma unroll
    for (int it = 0; it < 4; ++it) {
        int j = it * 256 + tid;            // 0..1023 -> (l,m)
        int m = j & 63;
        int l = j >> 6;
        const float* kp = kern + (m * K_PTS + l) * 3;
        float x = kp[0], y = kp[1], z = kp[2];
        ksp[l * N_KER + m] = make_float4(2.0f * LOG2E * x,
                                         2.0f * LOG2E * y,
                                         2.0f * LOG2E * z,
                                         -LOG2E * (x * x + y * y + z * z));
    }
    __syncthreads();

    const int wave = tid >> 6;
    const int m    = tid & 63;
    const float QS = 255.0f / 16.0f;

    // ---- phase A: S[q][m] u8, grid-stride over 16-point groups ----
    for (int base = blockIdx.x * PTS_PER_BLK; base < n;
         base += GRID_BLKS * PTS_PER_BLK) {
        int q0 = base + wave * 4;
        float gx[4], gy[4], gz[4], ea[4], acc[4];
        #pragma unroll
        for (int p = 0; p < 4; ++p) {
            int q = min(q0 + p, n - 1);
            float x = normal[q * 3 + 0];   // wave-uniform -> broadcast loads
            float y = normal[q * 3 + 1];
            float z = normal[q * 3 + 2];
            gx[p] = x; gy[p] = y; gz[p] = z;
            ea[p] = __builtin_amdgcn_exp2f(-LOG2E * (x * x + y * y + z * z));
            acc[p] = 0.0f;
        }
        #pragma unroll 4
        for (int l = 0; l < K_PTS; ++l) {
            float4 k4 = ksp[l * N_KER + m];
            #pragma unroll
            for (int p = 0; p < 4; ++p)
                acc[p] += __builtin_amdgcn_exp2f(
                    fmaf(gx[p], k4.x, fmaf(gy[p], k4.y, fmaf(gz[p], k4.z, k4.w))));
        }
        #pragma unroll
        for (int p = 0; p < 4; ++p)
            if (q0 + p < n) {
                float v = ea[p] * acc[p];
                S[(size_t)(q0 + p) * N_KER + m] = (unsigned char)(v * QS + 0.5f);
            }
    }

    // ---- device-scope visibility across XCD L2s, then grid-wide barrier ----
    __threadfence();
    cg::this_grid().sync();
    __threadfence();

    // ---- phase B: gather-add (R8 phase2, grid-stride) ----
    const unsigned int* S4 = (const unsigned int*)S;
    const float DQ = (16.0f / 255.0f) / 128.0f;
    const int total = n * 16;
    for (int t = blockIdx.x * 256 + tid; t < total; t += GRID_BLKS * 256) {
        int i = t >> 4;
        int h = t & 15;
        int a = neighbour[i * 3 + 0];
        int b = neighbour[i * 3 + 1];
        int c = neighbour[i * 3 + 2];
        unsigned int w0 = S4[t];
        unsigned int w1 = S4[a * 16 + h];
        unsigned int w2 = S4[b * 16 + h];
        unsigned int w3 = S4[c * 16 + h];
        float4 r;
        r.x = (float)(( w0        & 255u) + ( w1        & 255u) +
                      ( w2        & 255u) + ( w3        & 255u)) * DQ;
        r.y = (float)(((w0 >>  8) & 255u) + ((w1 >>  8) & 255u) +
                      ((w2 >>  8) & 255u) + ((w3 >>  8) & 255u)) * DQ;
        r.z = (float)(((w0 >> 16) & 255u) + ((w1 >> 16) & 255u) +
                      ((w2 >> 16) & 255u) + ((w3 >> 16) & 255u)) * DQ;
        r.w = (float)(( w0 >> 24        ) + ( w1 >> 24        ) +
                      ( w2 >> 24        ) + ( w3 >> 24        )) * DQ;
        out4[t] = r;
    }
}

// ======================= R8 fallback path (proven) ==========================
__global__ __launch_bounds__(256, 8) void corr_phase1(
    const float*   __restrict__ normal,
    const float*   __restrict__ kern,
    unsigned char* __restrict__ S,
    int n)
{
    __shared__ float4 ksp[K_PTS * N_KER];
    const int tid = threadIdx.x;
    #pragma unroll
    for (int it = 0; it < 4; ++it) {
        int j = it * 256 + tid;
        int m = j & 63;
        int l = j >> 6;
        const float* kp = kern + (m * K_PTS + l) * 3;
        float x = kp[0], y = kp[1], z = kp[2];
        ksp[l * N_KER + m] = make_float4(2.0f * LOG2E * x, 2.0f * LOG2E * y,
                                         2.0f * LOG2E * z,
                                         -LOG2E * (x * x + y * y + z * z));
    }
    __syncthreads();
    const int wave = tid >> 6;
    const int m    = tid & 63;
    const int q0   = blockIdx.x * 16 + wave * 4;
    float gx[4], gy[4], gz[4], ea[4], acc[4];
    #pragma unroll
    for (int p = 0; p < 4; ++p) {
        int q = min(q0 + p, n - 1);
        float x = normal[q * 3 + 0];
        float y = normal[q * 3 + 1];
        float z = normal[q * 3 + 2];
        gx[p] = x; gy[p] = y; gz[p] = z;
        ea[p] = __builtin_amdgcn_exp2f(-LOG2E * (x * x + y * y + z * z));
        acc[p] = 0.0f;
    }
    #pragma unroll 4
    for (int l = 0; l < K_PTS; ++l) {
        float4 k4 = ksp[l * N_KER + m];
        #pragma unroll
        for (int p = 0; p < 4; ++p)
            acc[p] += __builtin_amdgcn_exp2f(
                fmaf(gx[p], k4.x, fmaf(gy[p], k4.y, fmaf(gz[p], k4.z, k4.w))));
    }
    const float QS = 255.0f / 16.0f;
    #pragma unroll
    for (int p = 0; p < 4; ++p)
        if (q0 + p < n) {
            float v = ea[p] * acc[p];
            S[(size_t)(q0 + p) * N_KER + m] = (unsigned char)(v * QS + 0.5f);
        }
}

__global__ __launch_bounds__(256) void corr_phase2(
    const unsigned int* __restrict__ S4,
    const int*          __restrict__ neighbour,
    float4*             __restrict__ out4,
    int n)
{
    int t = blockIdx.x * 256 + threadIdx.x;
    if (t >= n * 16) return;
    int i = t >> 4;
    int h = t & 15;
    int a = neighbour[i * 3 + 0];
    int b = neighbour[i * 3 + 1];
    int c = neighbour[i * 3 + 2];
    unsigned int w0 = S4[t];
    unsigned int w1 = S4[a * 16 + h];
    unsigned int w2 = S4[b * 16 + h];
    unsigned int w3 = S4[c * 16 + h];
    const float DQ = (16.0f / 255.0f) / 128.0f;
    float4 r;
    r.x = (float)(( w0        & 255u) + ( w1        & 255u) +
                  ( w2        & 255u) + ( w3        & 255u)) * DQ;
    r.y = (float)(((w0 >>  8) & 255u) + ((w1 >>  8) & 255u) +
                  ((w2 >>  8) & 255u) + ((w3 >>  8) & 255u)) * DQ;
    r.z = (float)(((w0 >> 16) & 255u) + ((w1 >> 16) & 255u) +
                  ((w2 >> 16) & 255u) + ((w3 >> 16) & 255u)) * DQ;
    r.w = (float)(( w0 >> 24        ) + ( w1 >> 24        ) +
                  ( w2 >> 24        ) + ( w3 >> 24        )) * DQ;
    out4[t] = r;
}

extern "C" void kernel_launch(void* const* d_in, const int* in_sizes, int n_in,
                              void* d_out, int out_size, void* d_ws, size_t ws_size,
                              hipStream_t stream) {
    const float* normal    = (const float*)d_in[0];
    const int*   neighbour = (const int*)d_in[1];
    const float* kern      = (const float*)d_in[2];
    float*       out       = (float*)d_out;

    int n = in_sizes[0] / 3;
    size_t need = (size_t)n * N_KER;   // u8 table bytes

    if (ws_size >= need) {
        unsigned char* S = (unsigned char*)d_ws;
        float4* out4 = (float4*)out;
        void* args[] = { (void*)&normal, (void*)&neighbour, (void*)&kern,
                         (void*)&S, (void*)&out4, (void*)&n };
        hipError_t err = hipLaunchCooperativeKernel(
            (const void*)corr_coop, dim3(GRID_BLKS), dim3(256), args, 0, stream);
        if (err == hipSuccess) return;
        // cooperative rejected -> proven R8 two-kernel path
        int blocks1 = (n + 15) / 16;
        corr_phase1<<<blocks1, 256, 0, stream>>>(normal, kern, S, n);
        int blocks2 = (n * 16 + 255) / 256;
        corr_phase2<<<blocks2, 256, 0, stream>>>((const unsigned int*)S,
                                                 neighbour, (float4*)out, n);
    } else {
        // ws too small: shouldn't happen (need = 3.2 MB), but stay correct:
        // compute fused directly (recompute S 4x) via phase1-style math.
        // Reuse coop kernel path is impossible without ws; fall back to a
        // simple fused grid: one wave per point.
        // (R4-proven fused kernel)
        // -- inline minimal fused launch --
        struct L {
            static __global__ __launch_bounds__(256, 8) void f(
                const float* __restrict__ normal,
                const int*   __restrict__ neighbour,
                const float* __restrict__ kern,
                float*       __restrict__ out,
                int n);
        };
        // fallback uses corr_phase-style fused kernel below
        extern __global__ void corr_fused_k(const float*, const int*,
                                            const float*, float*, int);
        corr_fused_k<<<(n + 3) / 4, 256, 0, stream>>>(normal, neighbour, kern,
                                                      out, n);
    }
}

// R4-proven fused fallback (only used if ws_size < 3.2 MB)
__global__ __launch_bounds__(256, 8) void corr_fused_k(
    const float* __restrict__ normal,
    const int*   __restrict__ neighbour,
    const float* __restrict__ kern,
    float*       __restrict__ out,
    int n)
{
    __shared__ float4 ksp[K_PTS * N_KER];
    const int tid = threadIdx.x;
    #pragma unroll
    for (int it = 0; it < 4; ++it) {
        int j = it * 256 + tid;
        int m = j & 63;
        int l = j >> 6;
        const float* kp = kern + (m * K_PTS + l) * 3;
        float x = kp[0], y = kp[1], z = kp[2];
        ksp[l * N_KER + m] = make_float4(2.0f * LOG2E * x, 2.0f * LOG2E * y,
                                         2.0f * LOG2E * z,
                                         -LOG2E * (x * x + y * y + z * z));
    }
    __syncthreads();
    const int wave = tid >> 6;
    const int m    = tid & 63;
    const int i    = blockIdx.x * 4 + wave;
    if (i >= n) return;
    const int ia = neighbour[i * 3 + 0];
    const int ib = neighbour[i * 3 + 1];
    const int ic = neighbour[i * 3 + 2];
    int idxs[4] = { i, ia, ib, ic };
    float gx[4], gy[4], gz[4], ea[4], acc[4];
    #pragma unroll
    for (int p = 0; p < 4; ++p) {
        int q = idxs[p];
        float x = normal[q * 3 + 0];
        float y = normal[q * 3 + 1];
        float z = normal[q * 3 + 2];
        gx[p] = x; gy[p] = y; gz[p] = z;
        ea[p] = __builtin_amdgcn_exp2f(-LOG2E * (x * x + y * y + z * z));
        acc[p] = 0.0f;
    }
    #pragma unroll 4
    for (int l = 0; l < K_PTS; ++l) {
        float4 k4 = ksp[l * N_KER + m];
        #pragma unroll
        for (int p = 0; p < 4; ++p)
            acc[p] += __builtin_amdgcn_exp2f(
                fmaf(gx[p], k4.x, fmaf(gy[p], k4.y, fmaf(gz[p], k4.z, k4.w))));
    }
    float s = ea[0] * acc[0] + ea[1] * acc[1] + ea[2] * acc[2] + ea[3] * acc[3];
    out[(size_t)i * N_KER + m] = s * (1.0f / 128.0f);
}

// Round 10
// 80.664 us; speedup vs baseline: 6.3469x; 6.3469x over previous
//
#include <hip/hip_runtime.h>

#define N_KER 64
#define K_PTS 16
#define LOG2E 1.44269504088896340736f

// ============================================================================
// out[i][m] = (1/128) * (S[i][m]+S[a][m]+S[b][m]+S[c][m]),
// S[q][m] = sum_l exp(-||g_q - k[m][l]||^2), S stored u8 (R8-proven,
// absmax 1.22e-3 vs 3.4e-3 threshold).
// R10: R9's cooperative fusion REVERTED (grid.sync spun 420us: 93% occupancy,
// 2.5% VALUBusy). Back to R8's two-kernel path; one variable: phase1 now
// 8 points/wave (6250 waves vs 12500) — amortizes staging+prologue toward the
// ~5us trans-pipe floor. Live state ~50 VGPR, under the 64 boundary (R3
// lesson) enforced by __launch_bounds__(256,8).
// ============================================================================

// ---- Phase 1: S[q][m] u8; lane = m; 4 waves x 8 points per block ----
__global__ __launch_bounds__(256, 8) void corr_phase1(
    const float*   __restrict__ normal,
    const float*   __restrict__ kern,
    unsigned char* __restrict__ S,
    int n)
{
    __shared__ float4 ksp[K_PTS * N_KER];   // 16 KB [l][m], conflict-free (R3+)

    const int tid = threadIdx.x;
    #pragma unroll
    for (int it = 0; it < 4; ++it) {
        int j = it * 256 + tid;            // 0..1023 -> (l,m)
        int m = j & 63;
        int l = j >> 6;
        const float* kp = kern + (m * K_PTS + l) * 3;
        float x = kp[0], y = kp[1], z = kp[2];
        ksp[l * N_KER + m] = make_float4(2.0f * LOG2E * x,
                                         2.0f * LOG2E * y,
                                         2.0f * LOG2E * z,
                                         -LOG2E * (x * x + y * y + z * z));
    }
    __syncthreads();

    const int wave = tid >> 6;
    const int m    = tid & 63;
    const int q0   = blockIdx.x * 32 + wave * 8;   // 8 points per wave

    float gx[8], gy[8], gz[8], ea[8], acc[8];
    #pragma unroll
    for (int p = 0; p < 8; ++p) {
        int q = min(q0 + p, n - 1);
        float x = normal[q * 3 + 0];    // wave-uniform -> broadcast loads
        float y = normal[q * 3 + 1];
        float z = normal[q * 3 + 2];
        gx[p] = x; gy[p] = y; gz[p] = z;
        ea[p] = __builtin_amdgcn_exp2f(-LOG2E * (x * x + y * y + z * z));
        acc[p] = 0.0f;
    }

    // 16 l-steps x 8 points: 1 ds_read_b128 -> 8 exps; unroll 4 keeps
    // VGPR moderate (R3 lesson: crossing 64 halves occupancy).
    #pragma unroll 4
    for (int l = 0; l < K_PTS; ++l) {
        float4 k4 = ksp[l * N_KER + m];
        #pragma unroll
        for (int p = 0; p < 8; ++p)
            acc[p] += __builtin_amdgcn_exp2f(
                fmaf(gx[p], k4.x, fmaf(gy[p], k4.y, fmaf(gz[p], k4.z, k4.w))));
    }

    // u8 quantize: v in (0,16], q = v*255/16 + 0.5 truncated; contiguous
    // byte stores (64B txn per point per wave).
    const float QS = 255.0f / 16.0f;
    #pragma unroll
    for (int p = 0; p < 8; ++p)
        if (q0 + p < n) {
            float v = ea[p] * acc[p];
            S[(size_t)(q0 + p) * N_KER + m] = (unsigned char)(v * QS + 0.5f);
        }
}

// ---- Phase 2 (R8-proven, untouched): 16 threads/point; 4 u32 row-word
// loads, exact integer byte-lane sums, one dequant mul, float4 store. ----
__global__ __launch_bounds__(256) void corr_phase2(
    const unsigned int* __restrict__ S4,     // u8 rows viewed as 16 u32 words
    const int*          __restrict__ neighbour,
    float4*             __restrict__ out4,
    int n)
{
    int t = blockIdx.x * 256 + threadIdx.x;  // word index == i*16 + h
    if (t >= n * 16) return;
    int i = t >> 4;
    int a = neighbour[i * 3 + 0];
    int b = neighbour[i * 3 + 1];
    int c = neighbour[i * 3 + 2];
    int h = t & 15;
    unsigned int w0 = S4[t];                 // self: coalesced
    unsigned int w1 = S4[a * 16 + h];        // 64B row segments, L2-resident
    unsigned int w2 = S4[b * 16 + h];
    unsigned int w3 = S4[c * 16 + h];
    const float DQ = (16.0f / 255.0f) / 128.0f;
    float4 r;
    r.x = (float)(( w0        & 255u) + ( w1        & 255u) +
                  ( w2        & 255u) + ( w3        & 255u)) * DQ;
    r.y = (float)(((w0 >>  8) & 255u) + ((w1 >>  8) & 255u) +
                  ((w2 >>  8) & 255u) + ((w3 >>  8) & 255u)) * DQ;
    r.z = (float)(((w0 >> 16) & 255u) + ((w1 >> 16) & 255u) +
                  ((w2 >> 16) & 255u) + ((w3 >> 16) & 255u)) * DQ;
    r.w = (float)(( w0 >> 24        ) + ( w1 >> 24        ) +
                  ( w2 >> 24        ) + ( w3 >> 24        )) * DQ;
    out4[t] = r;
}

// ---- Fallback (R4 fused kernel, proven) if ws too small ----
__global__ __launch_bounds__(256, 8) void corr_fused(
    const float* __restrict__ normal,
    const int*   __restrict__ neighbour,
    const float* __restrict__ kern,
    float*       __restrict__ out,
    int n)
{
    __shared__ float4 ksp[K_PTS * N_KER];
    const int tid = threadIdx.x;
    #pragma unroll
    for (int it = 0; it < 4; ++it) {
        int j = it * 256 + tid;
        int m = j & 63;
        int l = j >> 6;
        const float* kp = kern + (m * K_PTS + l) * 3;
        float x = kp[0], y = kp[1], z = kp[2];
        ksp[l * N_KER + m] = make_float4(2.0f * LOG2E * x, 2.0f * LOG2E * y,
                                         2.0f * LOG2E * z,
                                         -LOG2E * (x * x + y * y + z * z));
    }
    __syncthreads();
    const int wave = tid >> 6;
    const int m    = tid & 63;
    const int i    = blockIdx.x * 4 + wave;
    if (i >= n) return;
    const int ia = neighbour[i * 3 + 0];
    const int ib = neighbour[i * 3 + 1];
    const int ic = neighbour[i * 3 + 2];
    int idxs[4] = { i, ia, ib, ic };
    float gx[4], gy[4], gz[4], ea[4], acc[4];
    #pragma unroll
    for (int p = 0; p < 4; ++p) {
        int q = idxs[p];
        float x = normal[q * 3 + 0];
        float y = normal[q * 3 + 1];
        float z = normal[q * 3 + 2];
        gx[p] = x; gy[p] = y; gz[p] = z;
        ea[p] = __builtin_amdgcn_exp2f(-LOG2E * (x * x + y * y + z * z));
        acc[p] = 0.0f;
    }
    #pragma unroll 4
    for (int l = 0; l < K_PTS; ++l) {
        float4 k4 = ksp[l * N_KER + m];
        #pragma unroll
        for (int p = 0; p < 4; ++p)
            acc[p] += __builtin_amdgcn_exp2f(
                fmaf(gx[p], k4.x, fmaf(gy[p], k4.y, fmaf(gz[p], k4.z, k4.w))));
    }
    float s = ea[0] * acc[0] + ea[1] * acc[1] + ea[2] * acc[2] + ea[3] * acc[3];
    out[(size_t)i * N_KER + m] = s * (1.0f / 128.0f);
}

extern "C" void kernel_launch(void* const* d_in, const int* in_sizes, int n_in,
                              void* d_out, int out_size, void* d_ws, size_t ws_size,
                              hipStream_t stream) {
    const float* normal    = (const float*)d_in[0];
    const int*   neighbour = (const int*)d_in[1];
    const float* kern      = (const float*)d_in[2];
    float*       out       = (float*)d_out;

    int n = in_sizes[0] / 3;
    size_t need = (size_t)n * N_KER;               // u8 table bytes

    if (ws_size >= need) {
        unsigned char* S = (unsigned char*)d_ws;
        int blocks1 = (n + 31) / 32;               // 8 q/wave, 4 waves
        corr_phase1<<<blocks1, 256, 0, stream>>>(normal, kern, S, n);
        int blocks2 = (n * 16 + 255) / 256;
        corr_phase2<<<blocks2, 256, 0, stream>>>((const unsigned int*)S,
                                                 neighbour, (float4*)out, n);
    } else {
        int blocks = (n + 3) / 4;
        corr_fused<<<blocks, 256, 0, stream>>>(normal, neighbour, kern, out, n);
    }
}